// Round 10
// baseline (35.548 us; speedup 1.0000x reference)
//
#include <hip/hip_runtime.h>
#include <hip/hip_bf16.h>

// Problem constants: features [16, 512, 56, 56] f32, k=3 -> d=1
#define BB 16
#define CC 512
#define HH 56
#define WW 56
#define HW (HH * WW)
#define NPIX (BB * HW)   // 50176 output pixels
#define CGROUPS 16

typedef float v4f __attribute__((ext_vector_type(4)));

__device__ __forceinline__ float shfl64(float v, int srcLane) {
    return __shfl(v, srcLane, 64);
}

// Proven math (R1..R9, absmax <= 2e-3 < 9e-3); masks & 1/9 cancel in cosine:
//   V(y)  = mym*g(y-1) + g(y) + myp*g(y+1)
//   w3(y) = mym*g(y)   + g(cl(y+1)) + myp*g(cl(y+2))
//   w4(y) = mym*g(cl(y-2)) + g(cl(y-1)) + myp*g(y)
//   f1 = mxm*V(cl(x-2)) + V(cl(x-1)) + mxp*V(x);  f2 = mxm*V(x) + V(cl(x+1)) + mxp*V(cl(x+2))
//   f3 = mxm*w3(cl(x-1)) + w3(x) + mxp*w3(cl(x+1)); f4 same on w4
// R10: 2 output rows per thread. Interior identities (all y-masks=1):
//   Sa=R0+R1+R2=w4(y), Sb=R1+R2+R3=V(y)=w4(y+1), Sc=R2+R3+R4=V(y+1)=w3(y),
//   Sd=R3+R4+R5=w3(y+1)  -> 6 loads & 12 shuffles per (4ch x 2 rows).
// Wave = 2 rows. lane = sc*16 + q (sc = channel subgroup, q = x-quad, q<14 active).
// Interior: inline-asm dwordx4 x6 (one vaddr, imm offsets -448..672) with
// vmcnt(6)-counted double buffer (R9-proven). Boundary row-pairs: C path.
template <int NITER, bool WRITE_OUT>
__global__ __launch_bounds__(256, 4) void ComputeTotalSim_84267258347855_kernel(
    const float* __restrict__ feat, float* __restrict__ ws, float* __restrict__ out) {
    const int wave = threadIdx.x >> 6;
    const int lane = threadIdx.x & 63;
    const int q = lane & 15;
    const int sc = lane >> 4;
    const int qs = (q <= 13) ? q : 13;  // idle lanes load safe real data
    const int x0 = 4 * qs;
    const int b = blockIdx.z;
    const int cg = blockIdx.x;
    const int ys = blockIdx.y * 8 + 2 * wave;  // this wave's rows: ys, ys+1

    const float mxm0 = (q == 0) ? 0.f : 1.f;   // x>=1 fails only at j=0,q=0
    const float mxp3 = (q >= 13) ? 0.f : 1.f;  // x<=54 fails only at j=3,q=13

    // channels: cg*(4*NITER) + 4*k + sc
    const float* p = feat + ((size_t)b * CC + (size_t)cg * (4 * NITER) + sc) * HW;

    // 48 named accumulators (s = row ys, t = row ys+1); NO arrays -> no scratch
    float sA0 = 0, sA1 = 0, sA2 = 0, sA3 = 0, sB0 = 0, sB1 = 0, sB2 = 0, sB3 = 0;
    float sC0 = 0, sC1 = 0, sC2 = 0, sC3 = 0, sD0 = 0, sD1 = 0, sD2 = 0, sD3 = 0;
    float sE0 = 0, sE1 = 0, sE2 = 0, sE3 = 0, sF0 = 0, sF1 = 0, sF2 = 0, sF3 = 0;
    float tA0 = 0, tA1 = 0, tA2 = 0, tA3 = 0, tB0 = 0, tB1 = 0, tB2 = 0, tB3 = 0;
    float tC0 = 0, tC1 = 0, tC2 = 0, tC3 = 0, tD0 = 0, tD1 = 0, tD2 = 0, tD3 = 0;
    float tE0 = 0, tE1 = 0, tE2 = 0, tE3 = 0, tF0 = 0, tF1 = 0, tF2 = 0, tF3 = 0;

// interior shared step: rows R0..R5 = g(ys-2..ys+3), all y-masks = 1
#define SHARED2(R0, R1, R2, R3, R4, R5)                                          \
    {                                                                            \
        const v4f t12 = R1 + R2, t34 = R3 + R4;                                  \
        const v4f Sa = R0 + t12, Sb = t12 + R3, Sc = t34 + R2, Sd = t34 + R5;    \
        float aL = shfl64(Sa.w, lane - 1), aR = shfl64(Sa.x, lane + 1);          \
        float bL2 = shfl64(Sb.z, lane - 1), bL1 = shfl64(Sb.w, lane - 1);        \
        float bR1 = shfl64(Sb.x, lane + 1), bR2 = shfl64(Sb.y, lane + 1);        \
        float cL2 = shfl64(Sc.z, lane - 1), cL1 = shfl64(Sc.w, lane - 1);        \
        float cR1 = shfl64(Sc.x, lane + 1), cR2 = shfl64(Sc.y, lane + 1);        \
        float dL = shfl64(Sd.w, lane - 1), dR = shfl64(Sd.x, lane + 1);          \
        if (q == 0) { aL = Sa.x; bL2 = Sb.x; bL1 = Sb.x; cL2 = Sc.x; cL1 = Sc.x; dL = Sd.x; } \
        if (q >= 13) { aR = Sa.w; bR1 = Sb.w; bR2 = Sb.w; cR1 = Sc.w; cR2 = Sc.w; dR = Sd.w; } \
        { /* row ys: V=Sb, w3=Sc, w4=Sa */                                       \
            const float f10 = fmaf(mxm0, bL2, bL1 + Sb.x), f11 = bL1 + Sb.x + Sb.y;  \
            const float f12 = Sb.x + Sb.y + Sb.z, f13 = fmaf(mxp3, Sb.w, Sb.y + Sb.z); \
            const float f20 = fmaf(mxm0, Sb.x, Sb.y + Sb.z), f21 = Sb.y + Sb.z + Sb.w; \
            const float f22 = Sb.z + Sb.w + bR1, f23 = fmaf(mxp3, bR2, Sb.w + bR1);  \
            const float f30 = fmaf(mxm0, cL1, Sc.x + Sc.y), f31 = Sc.x + Sc.y + Sc.z; \
            const float f32 = Sc.y + Sc.z + Sc.w, f33 = fmaf(mxp3, cR1, Sc.z + Sc.w); \
            const float f40 = fmaf(mxm0, aL, Sa.x + Sa.y), f41 = Sa.x + Sa.y + Sa.z; \
            const float f42 = Sa.y + Sa.z + Sa.w, f43 = fmaf(mxp3, aR, Sa.z + Sa.w); \
            sA0 = fmaf(f10, f20, sA0); sA1 = fmaf(f11, f21, sA1);                \
            sA2 = fmaf(f12, f22, sA2); sA3 = fmaf(f13, f23, sA3);                \
            sB0 = fmaf(f10, f10, sB0); sB1 = fmaf(f11, f11, sB1);                \
            sB2 = fmaf(f12, f12, sB2); sB3 = fmaf(f13, f13, sB3);                \
            sC0 = fmaf(f20, f20, sC0); sC1 = fmaf(f21, f21, sC1);                \
            sC2 = fmaf(f22, f22, sC2); sC3 = fmaf(f23, f23, sC3);                \
            sD0 = fmaf(f30, f40, sD0); sD1 = fmaf(f31, f41, sD1);                \
            sD2 = fmaf(f32, f42, sD2); sD3 = fmaf(f33, f43, sD3);                \
            sE0 = fmaf(f30, f30, sE0); sE1 = fmaf(f31, f31, sE1);                \
            sE2 = fmaf(f32, f32, sE2); sE3 = fmaf(f33, f33, sE3);                \
            sF0 = fmaf(f40, f40, sF0); sF1 = fmaf(f41, f41, sF1);                \
            sF2 = fmaf(f42, f42, sF2); sF3 = fmaf(f43, f43, sF3);                \
        }                                                                        \
        { /* row ys+1: V=Sc, w3=Sd, w4=Sb */                                     \
            const float f10 = fmaf(mxm0, cL2, cL1 + Sc.x), f11 = cL1 + Sc.x + Sc.y;  \
            const float f12 = Sc.x + Sc.y + Sc.z, f13 = fmaf(mxp3, Sc.w, Sc.y + Sc.z); \
            const float f20 = fmaf(mxm0, Sc.x, Sc.y + Sc.z), f21 = Sc.y + Sc.z + Sc.w; \
            const float f22 = Sc.z + Sc.w + cR1, f23 = fmaf(mxp3, cR2, Sc.w + cR1);  \
            const float f30 = fmaf(mxm0, dL, Sd.x + Sd.y), f31 = Sd.x + Sd.y + Sd.z; \
            const float f32 = Sd.y + Sd.z + Sd.w, f33 = fmaf(mxp3, dR, Sd.z + Sd.w); \
            const float f40 = fmaf(mxm0, bL1, Sb.x + Sb.y), f41 = Sb.x + Sb.y + Sb.z; \
            const float f42 = Sb.y + Sb.z + Sb.w, f43 = fmaf(mxp3, bR1, Sb.z + Sb.w); \
            tA0 = fmaf(f10, f20, tA0); tA1 = fmaf(f11, f21, tA1);                \
            tA2 = fmaf(f12, f22, tA2); tA3 = fmaf(f13, f23, tA3);                \
            tB0 = fmaf(f10, f10, tB0); tB1 = fmaf(f11, f11, tB1);                \
            tB2 = fmaf(f12, f12, tB2); tB3 = fmaf(f13, f13, tB3);                \
            tC0 = fmaf(f20, f20, tC0); tC1 = fmaf(f21, f21, tC1);                \
            tC2 = fmaf(f22, f22, tC2); tC3 = fmaf(f23, f23, tC3);                \
            tD0 = fmaf(f30, f40, tD0); tD1 = fmaf(f31, f41, tD1);                \
            tD2 = fmaf(f32, f42, tD2); tD3 = fmaf(f33, f43, tD3);                \
            tE0 = fmaf(f30, f30, tE0); tE1 = fmaf(f31, f31, tE1);                \
            tE2 = fmaf(f32, f32, tE2); tE3 = fmaf(f33, f33, tE3);                \
            tF0 = fmaf(f40, f40, tF0); tF1 = fmaf(f41, f41, tF1);                \
            tF2 = fmaf(f42, f42, tF2); tF3 = fmaf(f43, f43, tF3);                \
        }                                                                        \
    }

// boundary per-row step (R9 STEP with parameterized masks + accum prefix)
#define STEPB(A0_, A1_, A2_, A3_, A4_, MYM, MYP, P)                              \
    {                                                                            \
        const float Vx = fmaf(MYM, A1_.x, fmaf(MYP, A3_.x, A2_.x));              \
        const float Vy = fmaf(MYM, A1_.y, fmaf(MYP, A3_.y, A2_.y));              \
        const float Vz = fmaf(MYM, A1_.z, fmaf(MYP, A3_.z, A2_.z));              \
        const float Vw = fmaf(MYM, A1_.w, fmaf(MYP, A3_.w, A2_.w));              \
        const float u3x = fmaf(MYM, A2_.x, fmaf(MYP, A4_.x, A3_.x));             \
        const float u3y = fmaf(MYM, A2_.y, fmaf(MYP, A4_.y, A3_.y));             \
        const float u3z = fmaf(MYM, A2_.z, fmaf(MYP, A4_.z, A3_.z));             \
        const float u3w = fmaf(MYM, A2_.w, fmaf(MYP, A4_.w, A3_.w));             \
        const float u4x = fmaf(MYM, A0_.x, fmaf(MYP, A2_.x, A1_.x));             \
        const float u4y = fmaf(MYM, A0_.y, fmaf(MYP, A2_.y, A1_.y));             \
        const float u4z = fmaf(MYM, A0_.z, fmaf(MYP, A2_.z, A1_.z));             \
        const float u4w = fmaf(MYM, A0_.w, fmaf(MYP, A2_.w, A1_.w));             \
        float Vm2 = shfl64(Vz, lane - 1), Vm1 = shfl64(Vw, lane - 1);            \
        float Vp4 = shfl64(Vx, lane + 1), Vp5 = shfl64(Vy, lane + 1);            \
        float w3m = shfl64(u3w, lane - 1), w3p = shfl64(u3x, lane + 1);          \
        float w4m = shfl64(u4w, lane - 1), w4p = shfl64(u4x, lane + 1);          \
        if (q == 0) { Vm2 = Vx; Vm1 = Vx; w3m = u3x; w4m = u4x; }                \
        if (q >= 13) { Vp4 = Vw; Vp5 = Vw; w3p = u3w; w4p = u4w; }               \
        const float f10 = fmaf(mxm0, Vm2, Vm1 + Vx), f11 = Vm1 + Vx + Vy;        \
        const float f12 = Vx + Vy + Vz, f13 = fmaf(mxp3, Vw, Vy + Vz);           \
        const float f20 = fmaf(mxm0, Vx, Vy + Vz), f21 = Vy + Vz + Vw;           \
        const float f22 = Vz + Vw + Vp4, f23 = fmaf(mxp3, Vp5, Vw + Vp4);        \
        const float f30 = fmaf(mxm0, w3m, u3x + u3y), f31 = u3x + u3y + u3z;     \
        const float f32 = u3y + u3z + u3w, f33 = fmaf(mxp3, w3p, u3z + u3w);     \
        const float f40 = fmaf(mxm0, w4m, u4x + u4y), f41 = u4x + u4y + u4z;     \
        const float f42 = u4y + u4z + u4w, f43 = fmaf(mxp3, w4p, u4z + u4w);     \
        P##A0 = fmaf(f10, f20, P##A0); P##A1 = fmaf(f11, f21, P##A1);            \
        P##A2 = fmaf(f12, f22, P##A2); P##A3 = fmaf(f13, f23, P##A3);            \
        P##B0 = fmaf(f10, f10, P##B0); P##B1 = fmaf(f11, f11, P##B1);            \
        P##B2 = fmaf(f12, f12, P##B2); P##B3 = fmaf(f13, f13, P##B3);            \
        P##C0 = fmaf(f20, f20, P##C0); P##C1 = fmaf(f21, f21, P##C1);            \
        P##C2 = fmaf(f22, f22, P##C2); P##C3 = fmaf(f23, f23, P##C3);            \
        P##D0 = fmaf(f30, f40, P##D0); P##D1 = fmaf(f31, f41, P##D1);            \
        P##D2 = fmaf(f32, f42, P##D2); P##D3 = fmaf(f33, f43, P##D3);            \
        P##E0 = fmaf(f30, f30, P##E0); P##E1 = fmaf(f31, f31, P##E1);            \
        P##E2 = fmaf(f32, f32, P##E2); P##E3 = fmaf(f33, f33, P##E3);            \
        P##F0 = fmaf(f40, f40, P##F0); P##F1 = fmaf(f41, f41, P##F1);            \
        P##F2 = fmaf(f42, f42, P##F2); P##F3 = fmaf(f43, f43, P##F3);            \
    }

#define LOAD6(R0, R1, R2, R3, R4, R5, PC)                                                  \
    asm volatile("global_load_dwordx4 %0, %1, off offset:-448" : "=&v"(R0) : "v"(PC));     \
    asm volatile("global_load_dwordx4 %0, %1, off offset:-224" : "=&v"(R1) : "v"(PC));     \
    asm volatile("global_load_dwordx4 %0, %1, off"             : "=&v"(R2) : "v"(PC));     \
    asm volatile("global_load_dwordx4 %0, %1, off offset:224"  : "=&v"(R3) : "v"(PC));     \
    asm volatile("global_load_dwordx4 %0, %1, off offset:448"  : "=&v"(R4) : "v"(PC));     \
    asm volatile("global_load_dwordx4 %0, %1, off offset:672"  : "=&v"(R5) : "v"(PC));

#define WAITV(N)                                          \
    asm volatile("s_waitcnt vmcnt(" #N ")" ::: "memory"); \
    __builtin_amdgcn_sched_barrier(0);

    if (ys >= 2 && ys <= 52) {
        // ---- interior: rows ys-2..ys+3 = imm offsets -448..+672 bytes ----
        v4f A0, A1, A2, A3, A4, A5, B0, B1, B2, B3, B4, B5;
        const float* pc = p + (ys * WW + x0);
        LOAD6(A0, A1, A2, A3, A4, A5, pc); pc += 4 * HW;
        LOAD6(B0, B1, B2, B3, B4, B5, pc); pc += 4 * HW;
        for (int k = 0; k + 4 <= NITER; k += 2) {
            WAITV(6);                                        // A ready, B in flight
            SHARED2(A0, A1, A2, A3, A4, A5);
            LOAD6(A0, A1, A2, A3, A4, A5, pc); pc += 4 * HW;
            WAITV(6);                                        // B ready, A' in flight
            SHARED2(B0, B1, B2, B3, B4, B5);
            LOAD6(B0, B1, B2, B3, B4, B5, pc); pc += 4 * HW;
        }
        WAITV(6);
        SHARED2(A0, A1, A2, A3, A4, A5);
        WAITV(0);
        SHARED2(B0, B1, B2, B3, B4, B5);
    } else {
        // ---- boundary row-pairs (ys==0 or ys==54): per-row clamped C path ----
        const float mymA = (ys >= 1) ? 1.f : 0.f;
        const float mypA = 1.f;                        // ys<=54 always here
        const float mymB = 1.f;                        // ys+1>=1 always
        const float mypB = (ys <= 53) ? 1.f : 0.f;
        const int a0 = ((ys - 2 < 0) ? 0 : ys - 2) * WW + x0;
        const int a1 = ((ys - 1 < 0) ? 0 : ys - 1) * WW + x0;
        const int a2 = ys * WW + x0;
        const int a3 = (ys + 1) * WW + x0;             // ys<=54 -> <=55 ok
        const int a4 = ((ys + 2 > 55) ? 55 : ys + 2) * WW + x0;
        const int b1 = a2, b2 = a3;                    // row ys+1 taps
        const int b0 = a1;                             // cl(ys-1)
        const int b3 = ((ys + 2 > 55) ? 55 : ys + 2) * WW + x0;
        const int b4 = ((ys + 3 > 55) ? 55 : ys + 3) * WW + x0;
        for (int k = 0; k < NITER; ++k, p += 4 * HW) {
            const v4f r0 = *(const v4f*)(p + a0), r1 = *(const v4f*)(p + a1),
                      r2 = *(const v4f*)(p + a2), r3 = *(const v4f*)(p + a3),
                      r4 = *(const v4f*)(p + a4);
            STEPB(r0, r1, r2, r3, r4, mymA, mypA, s);
            const v4f q0 = *(const v4f*)(p + b0), q1 = *(const v4f*)(p + b1),
                      q2 = *(const v4f*)(p + b2), q3 = *(const v4f*)(p + b3),
                      q4 = *(const v4f*)(p + b4);
            STEPB(q0, q1, q2, q3, q4, mymB, mypB, t);
        }
    }
#undef SHARED2
#undef STEPB
#undef LOAD6
#undef WAITV

    // ---- reduce across the 4 channel sub-groups (lanes q, q+16, q+32, q+48) ----
#define RED2(v) { v += __shfl_xor(v, 16, 64); v += __shfl_xor(v, 32, 64); }
    RED2(sA0) RED2(sA1) RED2(sA2) RED2(sA3) RED2(sB0) RED2(sB1) RED2(sB2) RED2(sB3)
    RED2(sC0) RED2(sC1) RED2(sC2) RED2(sC3) RED2(sD0) RED2(sD1) RED2(sD2) RED2(sD3)
    RED2(sE0) RED2(sE1) RED2(sE2) RED2(sE3) RED2(sF0) RED2(sF1) RED2(sF2) RED2(sF3)
    RED2(tA0) RED2(tA1) RED2(tA2) RED2(tA3) RED2(tB0) RED2(tB1) RED2(tB2) RED2(tB3)
    RED2(tC0) RED2(tC1) RED2(tC2) RED2(tC3) RED2(tD0) RED2(tD1) RED2(tD2) RED2(tD3)
    RED2(tE0) RED2(tE1) RED2(tE2) RED2(tE3) RED2(tF0) RED2(tF1) RED2(tF2) RED2(tF3)
#undef RED2

    if (lane < 14) {  // sc==0, q<14
        const int pix = b * HW + ys * WW + 4 * q;  // row ys; row ys+1 at pix+WW
        if (WRITE_OUT) {
            v4f r;
            r.x = (float)(0.5 * ((double)sA0 / sqrt((double)sB0 * (double)sC0) +
                                 (double)sD0 / sqrt((double)sE0 * (double)sF0)));
            r.y = (float)(0.5 * ((double)sA1 / sqrt((double)sB1 * (double)sC1) +
                                 (double)sD1 / sqrt((double)sE1 * (double)sF1)));
            r.z = (float)(0.5 * ((double)sA2 / sqrt((double)sB2 * (double)sC2) +
                                 (double)sD2 / sqrt((double)sE2 * (double)sF2)));
            r.w = (float)(0.5 * ((double)sA3 / sqrt((double)sB3 * (double)sC3) +
                                 (double)sD3 / sqrt((double)sE3 * (double)sF3)));
            *(v4f*)(out + pix) = r;
            r.x = (float)(0.5 * ((double)tA0 / sqrt((double)tB0 * (double)tC0) +
                                 (double)tD0 / sqrt((double)tE0 * (double)tF0)));
            r.y = (float)(0.5 * ((double)tA1 / sqrt((double)tB1 * (double)tC1) +
                                 (double)tD1 / sqrt((double)tE1 * (double)tF1)));
            r.z = (float)(0.5 * ((double)tA2 / sqrt((double)tB2 * (double)tC2) +
                                 (double)tD2 / sqrt((double)tE2 * (double)tF2)));
            r.w = (float)(0.5 * ((double)tA3 / sqrt((double)tB3 * (double)tC3) +
                                 (double)tD3 / sqrt((double)tE3 * (double)tF3)));
            *(v4f*)(out + pix + WW) = r;
        } else {
            float* slab = ws + (size_t)cg * 6 * NPIX;
            *(v4f*)(slab + 0 * NPIX + pix) = (v4f){sA0, sA1, sA2, sA3};
            *(v4f*)(slab + 1 * NPIX + pix) = (v4f){sB0, sB1, sB2, sB3};
            *(v4f*)(slab + 2 * NPIX + pix) = (v4f){sC0, sC1, sC2, sC3};
            *(v4f*)(slab + 3 * NPIX + pix) = (v4f){sD0, sD1, sD2, sD3};
            *(v4f*)(slab + 4 * NPIX + pix) = (v4f){sE0, sE1, sE2, sE3};
            *(v4f*)(slab + 5 * NPIX + pix) = (v4f){sF0, sF1, sF2, sF3};
            *(v4f*)(slab + 0 * NPIX + pix + WW) = (v4f){tA0, tA1, tA2, tA3};
            *(v4f*)(slab + 1 * NPIX + pix + WW) = (v4f){tB0, tB1, tB2, tB3};
            *(v4f*)(slab + 2 * NPIX + pix + WW) = (v4f){tC0, tC1, tC2, tC3};
            *(v4f*)(slab + 3 * NPIX + pix + WW) = (v4f){tD0, tD1, tD2, tD3};
            *(v4f*)(slab + 4 * NPIX + pix + WW) = (v4f){tE0, tE1, tE2, tE3};
            *(v4f*)(slab + 5 * NPIX + pix + WW) = (v4f){tF0, tF1, tF2, tF3};
        }
    }
}

__global__ void ComputeTotalSim_finalize(const float* __restrict__ ws,
                                         float* __restrict__ out) {
    const int i = blockIdx.x * blockDim.x + threadIdx.x;
    if (i < NPIX) {
        double a0 = 0, a1 = 0, a2 = 0, a3 = 0, a4 = 0, a5 = 0;
#pragma unroll
        for (int cg = 0; cg < CGROUPS; ++cg) {
            const float* slab = ws + (size_t)cg * 6 * NPIX;
            a0 += slab[0 * NPIX + i];
            a1 += slab[1 * NPIX + i];
            a2 += slab[2 * NPIX + i];
            a3 += slab[3 * NPIX + i];
            a4 += slab[4 * NPIX + i];
            a5 += slab[5 * NPIX + i];
        }
        out[i] = (float)(0.5 * (a0 / sqrt(a1 * a2) + a3 / sqrt(a4 * a5)));
    }
}

extern "C" void kernel_launch(void* const* d_in, const int* in_sizes, int n_in,
                              void* d_out, int out_size, void* d_ws, size_t ws_size,
                              hipStream_t stream) {
    const float* feat = (const float*)d_in[0];
    float* out = (float*)d_out;

    const size_t need = (size_t)CGROUPS * 6 * NPIX * sizeof(float);  // 19.3 MB
    if (ws_size >= need) {
        // Phase 1: per-cgroup slab partials (plain stores, every slot written
        // every call -> no memset needed). Phase 2: sum slabs + cosine.
        dim3 grid(CGROUPS, HH / 8, BB);  // 16 x 7 x 16 = 1792 blocks
        ComputeTotalSim_84267258347855_kernel<CC / (4 * CGROUPS), false>
            <<<grid, 256, 0, stream>>>(feat, (float*)d_ws, out);
        ComputeTotalSim_finalize<<<(NPIX + 255) / 256, 256, 0, stream>>>(
            (const float*)d_ws, out);
    } else {
        // Fallback: single cgroup covers all 512 channels, writes out directly.
        dim3 grid(1, HH / 8, BB);
        ComputeTotalSim_84267258347855_kernel<CC / 4, true>
            <<<grid, 256, 0, stream>>>(feat, nullptr, out);
    }
}

// Round 11
// 35.419 us; speedup vs baseline: 1.0036x; 1.0036x over previous
//
#include <hip/hip_runtime.h>
#include <hip/hip_bf16.h>

// Problem constants: features [16, 512, 56, 56] f32, k=3 -> d=1
#define BB 16
#define CC 512
#define HH 56
#define WW 56
#define HW (HH * WW)
#define NPIX (BB * HW)   // 50176 output pixels
#define CGROUPS 8

typedef float v4f __attribute__((ext_vector_type(4)));

__device__ __forceinline__ float shfl64(float v, int srcLane) {
    return __shfl(v, srcLane, 64);
}

// Proven math (R1..R10, absmax <= 2e-3 < 9e-3); masks & 1/9 cancel in cosine:
//   V  = mym*g(y-1) + g(y) + myp*g(y+1)
//   w3 = mym*g(y)   + g(cl(y+1)) + myp*g(cl(y+2))
//   w4 = mym*g(cl(y-2)) + g(cl(y-1)) + myp*g(y)
//   f1 = mxm*V(cl(x-2)) + V(cl(x-1)) + mxp*V(x)
//   f2 = mxm*V(x) + V(cl(x+1)) + mxp*V(cl(x+2))
//   f3 = mxm*w3(cl(x-1)) + w3(x) + mxp*w3(cl(x+1))
//   f4 = mxm*w4(cl(x-1)) + w4(x) + mxp*w4(cl(x+1))
// Wave = one row y (R9 geometry). lane = sc*16 + q: sc = channel sub-group
// (4 ch/iter), q = x-quad (float4/thread, q<14 active).
// R11: 3-deep counted-vmcnt pipeline (R9 was 2-deep). Fully static unroll of
// NITER=16; steady state s_waitcnt vmcnt(10) => 2 iterations (10 loads) always
// in flight; tail vmcnt(5)/vmcnt(0). R10's 2-row variant reverted (flat, +VGPR).
template <int NITER, bool WRITE_OUT>
__global__ __launch_bounds__(256, 4) void ComputeTotalSim_84267258347855_kernel(
    const float* __restrict__ feat, float* __restrict__ ws, float* __restrict__ out) {
    const int wave = threadIdx.x >> 6;
    const int lane = threadIdx.x & 63;
    const int sc = lane >> 4;
    const int q = lane & 15;
    const int qs = (q <= 13) ? q : 13;  // idle lanes load safe real data
    const int x0 = 4 * qs;
    const int b = blockIdx.z;
    const int cg = blockIdx.x;
    const int y = blockIdx.y * 4 + wave;

    const float mym = (y >= 1) ? 1.f : 0.f;
    const float myp = (y <= HH - 2) ? 1.f : 0.f;
    const float mxm0 = (q == 0) ? 0.f : 1.f;   // applies only at j=0
    const float mxp3 = (q >= 13) ? 0.f : 1.f;  // applies only at j=3

    const int ry0 = (y - 2 < 0) ? 0 : y - 2;
    const int ry1 = (y - 1 < 0) ? 0 : y - 1;
    const int ry3 = (y + 1 > HH - 1) ? HH - 1 : y + 1;
    const int ry4 = (y + 2 > HH - 1) ? HH - 1 : y + 2;
    const int o0 = ry0 * WW + x0, o1 = ry1 * WW + x0, o2 = y * WW + x0,
              o3 = ry3 * WW + x0, o4 = ry4 * WW + x0;

    // channels: cg*(4*NITER) + 4*k + sc, k = 0..NITER-1
    const float* p = feat + ((size_t)b * CC + (size_t)cg * (4 * NITER) + sc) * HW;

    // 24 named accumulators (NO arrays anywhere -> no scratch possible)
    float sA0 = 0, sA1 = 0, sA2 = 0, sA3 = 0;  // s12h
    float sB0 = 0, sB1 = 0, sB2 = 0, sB3 = 0;  // s11
    float sC0 = 0, sC1 = 0, sC2 = 0, sC3 = 0;  // s22
    float sD0 = 0, sD1 = 0, sD2 = 0, sD3 = 0;  // s12v
    float sE0 = 0, sE1 = 0, sE2 = 0, sE3 = 0;  // s33
    float sF0 = 0, sF1 = 0, sF2 = 0, sF3 = 0;  // s44

#define STEP(A0_, A1_, A2_, A3_, A4_)                                           \
    {                                                                           \
        const float Vx = fmaf(mym, A1_.x, fmaf(myp, A3_.x, A2_.x));             \
        const float Vy = fmaf(mym, A1_.y, fmaf(myp, A3_.y, A2_.y));             \
        const float Vz = fmaf(mym, A1_.z, fmaf(myp, A3_.z, A2_.z));             \
        const float Vw = fmaf(mym, A1_.w, fmaf(myp, A3_.w, A2_.w));             \
        const float t3x = fmaf(mym, A2_.x, fmaf(myp, A4_.x, A3_.x));            \
        const float t3y = fmaf(mym, A2_.y, fmaf(myp, A4_.y, A3_.y));            \
        const float t3z = fmaf(mym, A2_.z, fmaf(myp, A4_.z, A3_.z));            \
        const float t3w = fmaf(mym, A2_.w, fmaf(myp, A4_.w, A3_.w));            \
        const float t4x = fmaf(mym, A0_.x, fmaf(myp, A2_.x, A1_.x));            \
        const float t4y = fmaf(mym, A0_.y, fmaf(myp, A2_.y, A1_.y));            \
        const float t4z = fmaf(mym, A0_.z, fmaf(myp, A2_.z, A1_.z));            \
        const float t4w = fmaf(mym, A0_.w, fmaf(myp, A2_.w, A1_.w));            \
        float Vm2 = shfl64(Vz, lane - 1), Vm1 = shfl64(Vw, lane - 1);           \
        float Vp4 = shfl64(Vx, lane + 1), Vp5 = shfl64(Vy, lane + 1);           \
        float w3m = shfl64(t3w, lane - 1), w3p = shfl64(t3x, lane + 1);         \
        float w4m = shfl64(t4w, lane - 1), w4p = shfl64(t4x, lane + 1);         \
        if (q == 0) { Vm2 = Vx; Vm1 = Vx; w3m = t3x; w4m = t4x; }               \
        if (q >= 13) { Vp4 = Vw; Vp5 = Vw; w3p = t3w; w4p = t4w; }              \
        const float f10 = fmaf(mxm0, Vm2, Vm1 + Vx);                            \
        const float f11 = Vm1 + Vx + Vy;                                        \
        const float f12 = Vx + Vy + Vz;                                         \
        const float f13 = fmaf(mxp3, Vw, Vy + Vz);                              \
        const float f20 = fmaf(mxm0, Vx, Vy + Vz);                              \
        const float f21 = Vy + Vz + Vw;                                         \
        const float f22 = Vz + Vw + Vp4;                                        \
        const float f23 = fmaf(mxp3, Vp5, Vw + Vp4);                            \
        const float f30 = fmaf(mxm0, w3m, t3x + t3y);                           \
        const float f31 = t3x + t3y + t3z;                                      \
        const float f32 = t3y + t3z + t3w;                                      \
        const float f33 = fmaf(mxp3, w3p, t3z + t3w);                           \
        const float f40 = fmaf(mxm0, w4m, t4x + t4y);                           \
        const float f41 = t4x + t4y + t4z;                                      \
        const float f42 = t4y + t4z + t4w;                                      \
        const float f43 = fmaf(mxp3, w4p, t4z + t4w);                           \
        sA0 = fmaf(f10, f20, sA0); sA1 = fmaf(f11, f21, sA1);                   \
        sA2 = fmaf(f12, f22, sA2); sA3 = fmaf(f13, f23, sA3);                   \
        sB0 = fmaf(f10, f10, sB0); sB1 = fmaf(f11, f11, sB1);                   \
        sB2 = fmaf(f12, f12, sB2); sB3 = fmaf(f13, f13, sB3);                   \
        sC0 = fmaf(f20, f20, sC0); sC1 = fmaf(f21, f21, sC1);                   \
        sC2 = fmaf(f22, f22, sC2); sC3 = fmaf(f23, f23, sC3);                   \
        sD0 = fmaf(f30, f40, sD0); sD1 = fmaf(f31, f41, sD1);                   \
        sD2 = fmaf(f32, f42, sD2); sD3 = fmaf(f33, f43, sD3);                   \
        sE0 = fmaf(f30, f30, sE0); sE1 = fmaf(f31, f31, sE1);                   \
        sE2 = fmaf(f32, f32, sE2); sE3 = fmaf(f33, f33, sE3);                   \
        sF0 = fmaf(f40, f40, sF0); sF1 = fmaf(f41, f41, sF1);                   \
        sF2 = fmaf(f42, f42, sF2); sF3 = fmaf(f43, f43, sF3);                   \
    }

#define LOAD5(R0, R1, R2, R3, R4, PC)                                                      \
    asm volatile("global_load_dwordx4 %0, %1, off offset:-448" : "=&v"(R0) : "v"(PC));     \
    asm volatile("global_load_dwordx4 %0, %1, off offset:-224" : "=&v"(R1) : "v"(PC));     \
    asm volatile("global_load_dwordx4 %0, %1, off"             : "=&v"(R2) : "v"(PC));     \
    asm volatile("global_load_dwordx4 %0, %1, off offset:224"  : "=&v"(R3) : "v"(PC));     \
    asm volatile("global_load_dwordx4 %0, %1, off offset:448"  : "=&v"(R4) : "v"(PC));

#define LOAD5AT(R0, R1, R2, R3, R4, KK)                                          \
    { const float* _pck = pc0 + (size_t)(KK) * (4 * HW);                         \
      LOAD5(R0, R1, R2, R3, R4, _pck) }

#define WAITV(N)                                          \
    asm volatile("s_waitcnt vmcnt(" #N ")" ::: "memory"); \
    __builtin_amdgcn_sched_barrier(0);

// one fully-static pipeline stage: wait, consume, issue load for KK+3
#define ITER(KK, R0, R1, R2, R3, R4, WN)                                         \
    WAITV(WN)                                                                    \
    STEP(R0, R1, R2, R3, R4)                                                     \
    if ((KK) + 3 < 16) { LOAD5AT(R0, R1, R2, R3, R4, (KK) + 3) }

    if (NITER == 16 && blockIdx.y >= 1 && blockIdx.y <= 12) {
        // ---- interior rows (y in 4..51): imm offsets -448..+448, 3-deep ----
        v4f A0, A1, A2, A3, A4, B0, B1, B2, B3, B4, C0, C1, C2, C3, C4;
        const float* pc0 = p + o2;  // center-row per-lane address, iter 0
        LOAD5AT(A0, A1, A2, A3, A4, 0)
        LOAD5AT(B0, B1, B2, B3, B4, 1)
        LOAD5AT(C0, C1, C2, C3, C4, 2)
        ITER(0,  A0, A1, A2, A3, A4, 10)
        ITER(1,  B0, B1, B2, B3, B4, 10)
        ITER(2,  C0, C1, C2, C3, C4, 10)
        ITER(3,  A0, A1, A2, A3, A4, 10)
        ITER(4,  B0, B1, B2, B3, B4, 10)
        ITER(5,  C0, C1, C2, C3, C4, 10)
        ITER(6,  A0, A1, A2, A3, A4, 10)
        ITER(7,  B0, B1, B2, B3, B4, 10)
        ITER(8,  C0, C1, C2, C3, C4, 10)
        ITER(9,  A0, A1, A2, A3, A4, 10)
        ITER(10, B0, B1, B2, B3, B4, 10)
        ITER(11, C0, C1, C2, C3, C4, 10)
        ITER(12, A0, A1, A2, A3, A4, 10)
        ITER(13, B0, B1, B2, B3, B4, 10)
        ITER(14, C0, C1, C2, C3, C4, 5)
        ITER(15, A0, A1, A2, A3, A4, 0)
    } else {
        // ---- boundary strips / fallback: generic clamped C path (R9-proven) ----
        v4f A0, A1, A2, A3, A4, B0, B1, B2, B3, B4;
        A0 = *(const v4f*)(p + o0); A1 = *(const v4f*)(p + o1);
        A2 = *(const v4f*)(p + o2); A3 = *(const v4f*)(p + o3);
        A4 = *(const v4f*)(p + o4);
        p += 4 * HW;
        for (int k = 0; k + 2 <= NITER; k += 2) {
            B0 = *(const v4f*)(p + o0); B1 = *(const v4f*)(p + o1);
            B2 = *(const v4f*)(p + o2); B3 = *(const v4f*)(p + o3);
            B4 = *(const v4f*)(p + o4);
            STEP(A0, A1, A2, A3, A4);
            const float* pn = (k + 2 < NITER) ? p + 4 * HW : p;
            A0 = *(const v4f*)(pn + o0); A1 = *(const v4f*)(pn + o1);
            A2 = *(const v4f*)(pn + o2); A3 = *(const v4f*)(pn + o3);
            A4 = *(const v4f*)(pn + o4);
            STEP(B0, B1, B2, B3, B4);
            p = pn + 4 * HW;
        }
    }
#undef STEP
#undef LOAD5
#undef LOAD5AT
#undef WAITV
#undef ITER

    // ---- reduce across the 4 channel sub-groups (lanes q, q+16, q+32, q+48) ----
#define RED2(v) { v += __shfl_xor(v, 16, 64); v += __shfl_xor(v, 32, 64); }
    RED2(sA0) RED2(sA1) RED2(sA2) RED2(sA3)
    RED2(sB0) RED2(sB1) RED2(sB2) RED2(sB3)
    RED2(sC0) RED2(sC1) RED2(sC2) RED2(sC3)
    RED2(sD0) RED2(sD1) RED2(sD2) RED2(sD3)
    RED2(sE0) RED2(sE1) RED2(sE2) RED2(sE3)
    RED2(sF0) RED2(sF1) RED2(sF2) RED2(sF3)
#undef RED2

    if (lane < 14) {  // sc==0, q<14
        const int pix = b * HW + y * WW + 4 * q;
        if (WRITE_OUT) {
            v4f r;
            r.x = (float)(0.5 * ((double)sA0 / sqrt((double)sB0 * (double)sC0) +
                                 (double)sD0 / sqrt((double)sE0 * (double)sF0)));
            r.y = (float)(0.5 * ((double)sA1 / sqrt((double)sB1 * (double)sC1) +
                                 (double)sD1 / sqrt((double)sE1 * (double)sF1)));
            r.z = (float)(0.5 * ((double)sA2 / sqrt((double)sB2 * (double)sC2) +
                                 (double)sD2 / sqrt((double)sE2 * (double)sF2)));
            r.w = (float)(0.5 * ((double)sA3 / sqrt((double)sB3 * (double)sC3) +
                                 (double)sD3 / sqrt((double)sE3 * (double)sF3)));
            *(v4f*)(out + pix) = r;
        } else {
            float* slab = ws + (size_t)cg * 6 * NPIX;
            *(v4f*)(slab + 0 * NPIX + pix) = (v4f){sA0, sA1, sA2, sA3};
            *(v4f*)(slab + 1 * NPIX + pix) = (v4f){sB0, sB1, sB2, sB3};
            *(v4f*)(slab + 2 * NPIX + pix) = (v4f){sC0, sC1, sC2, sC3};
            *(v4f*)(slab + 3 * NPIX + pix) = (v4f){sD0, sD1, sD2, sD3};
            *(v4f*)(slab + 4 * NPIX + pix) = (v4f){sE0, sE1, sE2, sE3};
            *(v4f*)(slab + 5 * NPIX + pix) = (v4f){sF0, sF1, sF2, sF3};
        }
    }
}

__global__ void ComputeTotalSim_finalize(const float* __restrict__ ws,
                                         float* __restrict__ out) {
    const int i = blockIdx.x * blockDim.x + threadIdx.x;
    if (i < NPIX) {
        double a0 = 0, a1 = 0, a2 = 0, a3 = 0, a4 = 0, a5 = 0;
#pragma unroll
        for (int cg = 0; cg < CGROUPS; ++cg) {
            const float* slab = ws + (size_t)cg * 6 * NPIX;
            a0 += slab[0 * NPIX + i];
            a1 += slab[1 * NPIX + i];
            a2 += slab[2 * NPIX + i];
            a3 += slab[3 * NPIX + i];
            a4 += slab[4 * NPIX + i];
            a5 += slab[5 * NPIX + i];
        }
        out[i] = (float)(0.5 * (a0 / sqrt(a1 * a2) + a3 / sqrt(a4 * a5)));
    }
}

extern "C" void kernel_launch(void* const* d_in, const int* in_sizes, int n_in,
                              void* d_out, int out_size, void* d_ws, size_t ws_size,
                              hipStream_t stream) {
    const float* feat = (const float*)d_in[0];
    float* out = (float*)d_out;

    const size_t need = (size_t)CGROUPS * 6 * NPIX * sizeof(float);  // 9.6 MB
    if (ws_size >= need) {
        // Phase 1: per-cgroup slab partials (plain stores, every slot written
        // every call -> no memset needed). Phase 2: sum slabs + cosine.
        dim3 grid(CGROUPS, HH / 4, BB);  // 8 x 14 x 16 = 1792 blocks
        ComputeTotalSim_84267258347855_kernel<CC / (4 * CGROUPS), false>
            <<<grid, 256, 0, stream>>>(feat, (float*)d_ws, out);
        ComputeTotalSim_finalize<<<(NPIX + 255) / 256, 256, 0, stream>>>(
            (const float*)d_ws, out);
    } else {
        // Fallback: single cgroup covers all 512 channels, writes out directly.
        dim3 grid(1, HH / 4, BB);
        ComputeTotalSim_84267258347855_kernel<CC / 4, true>
            <<<grid, 256, 0, stream>>>(feat, nullptr, out);
    }
}

// Round 13
// 33.185 us; speedup vs baseline: 1.0712x; 1.0673x over previous
//
#include <hip/hip_runtime.h>
#include <hip/hip_bf16.h>

// Problem constants: features [16, 512, 56, 56] f32, k=3 -> d=1
#define BB 16
#define CC 512
#define HH 56
#define WW 56
#define HW (HH * WW)
#define NPIX (BB * HW)   // 50176 output pixels
#define CGROUPS 8

typedef float v4f __attribute__((ext_vector_type(4)));

// DPP lane shifts within each 16-lane row (= our sc channel group).
// CORRECTED vs R12 (which swapped directions; absmax 0.27):
//   "value from lane-1" = row_shr:1 (ctrl 0x111)  [HIP __shfl_up uses row_shr]
//   "value from lane+1" = row_shl:1 (ctrl 0x101)
// Invalid edge lanes (q=0 for shr, q=15 for shl) keep `old` (= own value),
// which the q==0 / q>=13 clamp fixups overwrite — same semantics as the old
// shfl64 whose cross-group values were also fixup-overwritten.
__device__ __forceinline__ float dpp_prev(float x) {  // dest[i] = src[i-1]
    return __int_as_float(__builtin_amdgcn_update_dpp(
        __float_as_int(x), __float_as_int(x), 0x111, 0xf, 0xf, false));
}
__device__ __forceinline__ float dpp_next(float x) {  // dest[i] = src[i+1]
    return __int_as_float(__builtin_amdgcn_update_dpp(
        __float_as_int(x), __float_as_int(x), 0x101, 0xf, 0xf, false));
}

// Proven math (R1..R11, absmax <= 2e-3 < 9e-3); masks & 1/9 cancel in cosine:
//   V  = mym*g(y-1) + g(y) + myp*g(y+1)
//   w3 = mym*g(y)   + g(cl(y+1)) + myp*g(cl(y+2))
//   w4 = mym*g(cl(y-2)) + g(cl(y-1)) + myp*g(y)
//   f1 = mxm*V(cl(x-2)) + V(cl(x-1)) + mxp*V(x)
//   f2 = mxm*V(x) + V(cl(x+1)) + mxp*V(cl(x+2))
//   f3 = mxm*w3(cl(x-1)) + w3(x) + mxp*w3(cl(x+1))
//   f4 = mxm*w4(cl(x-1)) + w4(x) + mxp*w4(cl(x+1))
// Wave = one row y (R9 geometry). lane = sc*16 + q: sc = channel sub-group
// (4 ch/iter), q = x-quad (float4/thread, q<14 active).
// R13 = R12 with corrected DPP directions: main loop has ZERO DS ops.
template <int NITER, bool WRITE_OUT>
__global__ __launch_bounds__(256, 4) void ComputeTotalSim_84267258347855_kernel(
    const float* __restrict__ feat, float* __restrict__ ws, float* __restrict__ out) {
    const int wave = threadIdx.x >> 6;
    const int lane = threadIdx.x & 63;
    const int sc = lane >> 4;
    const int q = lane & 15;
    const int qs = (q <= 13) ? q : 13;  // idle lanes load safe real data
    const int x0 = 4 * qs;
    const int b = blockIdx.z;
    const int cg = blockIdx.x;
    const int y = blockIdx.y * 4 + wave;

    const float mym = (y >= 1) ? 1.f : 0.f;
    const float myp = (y <= HH - 2) ? 1.f : 0.f;
    const float mxm0 = (q == 0) ? 0.f : 1.f;   // applies only at j=0
    const float mxp3 = (q >= 13) ? 0.f : 1.f;  // applies only at j=3

    const int ry0 = (y - 2 < 0) ? 0 : y - 2;
    const int ry1 = (y - 1 < 0) ? 0 : y - 1;
    const int ry3 = (y + 1 > HH - 1) ? HH - 1 : y + 1;
    const int ry4 = (y + 2 > HH - 1) ? HH - 1 : y + 2;
    const int o0 = ry0 * WW + x0, o1 = ry1 * WW + x0, o2 = y * WW + x0,
              o3 = ry3 * WW + x0, o4 = ry4 * WW + x0;

    // channels: cg*(4*NITER) + 4*k + sc, k = 0..NITER-1
    const float* p = feat + ((size_t)b * CC + (size_t)cg * (4 * NITER) + sc) * HW;

    // 24 named accumulators (NO arrays anywhere -> no scratch possible)
    float sA0 = 0, sA1 = 0, sA2 = 0, sA3 = 0;  // s12h
    float sB0 = 0, sB1 = 0, sB2 = 0, sB3 = 0;  // s11
    float sC0 = 0, sC1 = 0, sC2 = 0, sC3 = 0;  // s22
    float sD0 = 0, sD1 = 0, sD2 = 0, sD3 = 0;  // s12v
    float sE0 = 0, sE1 = 0, sE2 = 0, sE3 = 0;  // s33
    float sF0 = 0, sF1 = 0, sF2 = 0, sF3 = 0;  // s44

#define STEP(A0_, A1_, A2_, A3_, A4_)                                           \
    {                                                                           \
        const float Vx = fmaf(mym, A1_.x, fmaf(myp, A3_.x, A2_.x));             \
        const float Vy = fmaf(mym, A1_.y, fmaf(myp, A3_.y, A2_.y));             \
        const float Vz = fmaf(mym, A1_.z, fmaf(myp, A3_.z, A2_.z));             \
        const float Vw = fmaf(mym, A1_.w, fmaf(myp, A3_.w, A2_.w));             \
        const float t3x = fmaf(mym, A2_.x, fmaf(myp, A4_.x, A3_.x));            \
        const float t3y = fmaf(mym, A2_.y, fmaf(myp, A4_.y, A3_.y));            \
        const float t3z = fmaf(mym, A2_.z, fmaf(myp, A4_.z, A3_.z));            \
        const float t3w = fmaf(mym, A2_.w, fmaf(myp, A4_.w, A3_.w));            \
        const float t4x = fmaf(mym, A0_.x, fmaf(myp, A2_.x, A1_.x));            \
        const float t4y = fmaf(mym, A0_.y, fmaf(myp, A2_.y, A1_.y));            \
        const float t4z = fmaf(mym, A0_.z, fmaf(myp, A2_.z, A1_.z));            \
        const float t4w = fmaf(mym, A0_.w, fmaf(myp, A2_.w, A1_.w));            \
        float Vm2 = dpp_prev(Vz), Vm1 = dpp_prev(Vw);                           \
        float Vp4 = dpp_next(Vx), Vp5 = dpp_next(Vy);                           \
        float w3m = dpp_prev(t3w), w3p = dpp_next(t3x);                         \
        float w4m = dpp_prev(t4w), w4p = dpp_next(t4x);                         \
        if (q == 0) { Vm2 = Vx; Vm1 = Vx; w3m = t3x; w4m = t4x; }               \
        if (q >= 13) { Vp4 = Vw; Vp5 = Vw; w3p = t3w; w4p = t4w; }              \
        const float f10 = fmaf(mxm0, Vm2, Vm1 + Vx);                            \
        const float f11 = Vm1 + Vx + Vy;                                        \
        const float f12 = Vx + Vy + Vz;                                         \
        const float f13 = fmaf(mxp3, Vw, Vy + Vz);                              \
        const float f20 = fmaf(mxm0, Vx, Vy + Vz);                              \
        const float f21 = Vy + Vz + Vw;                                         \
        const float f22 = Vz + Vw + Vp4;                                        \
        const float f23 = fmaf(mxp3, Vp5, Vw + Vp4);                            \
        const float f30 = fmaf(mxm0, w3m, t3x + t3y);                           \
        const float f31 = t3x + t3y + t3z;                                      \
        const float f32 = t3y + t3z + t3w;                                      \
        const float f33 = fmaf(mxp3, w3p, t3z + t3w);                           \
        const float f40 = fmaf(mxm0, w4m, t4x + t4y);                           \
        const float f41 = t4x + t4y + t4z;                                      \
        const float f42 = t4y + t4z + t4w;                                      \
        const float f43 = fmaf(mxp3, w4p, t4z + t4w);                           \
        sA0 = fmaf(f10, f20, sA0); sA1 = fmaf(f11, f21, sA1);                   \
        sA2 = fmaf(f12, f22, sA2); sA3 = fmaf(f13, f23, sA3);                   \
        sB0 = fmaf(f10, f10, sB0); sB1 = fmaf(f11, f11, sB1);                   \
        sB2 = fmaf(f12, f12, sB2); sB3 = fmaf(f13, f13, sB3);                   \
        sC0 = fmaf(f20, f20, sC0); sC1 = fmaf(f21, f21, sC1);                   \
        sC2 = fmaf(f22, f22, sC2); sC3 = fmaf(f23, f23, sC3);                   \
        sD0 = fmaf(f30, f40, sD0); sD1 = fmaf(f31, f41, sD1);                   \
        sD2 = fmaf(f32, f42, sD2); sD3 = fmaf(f33, f43, sD3);                   \
        sE0 = fmaf(f30, f30, sE0); sE1 = fmaf(f31, f31, sE1);                   \
        sE2 = fmaf(f32, f32, sE2); sE3 = fmaf(f33, f33, sE3);                   \
        sF0 = fmaf(f40, f40, sF0); sF1 = fmaf(f41, f41, sF1);                   \
        sF2 = fmaf(f42, f42, sF2); sF3 = fmaf(f43, f43, sF3);                   \
    }

#define LOAD5(R0, R1, R2, R3, R4, PC)                                                      \
    asm volatile("global_load_dwordx4 %0, %1, off offset:-448" : "=&v"(R0) : "v"(PC));     \
    asm volatile("global_load_dwordx4 %0, %1, off offset:-224" : "=&v"(R1) : "v"(PC));     \
    asm volatile("global_load_dwordx4 %0, %1, off"             : "=&v"(R2) : "v"(PC));     \
    asm volatile("global_load_dwordx4 %0, %1, off offset:224"  : "=&v"(R3) : "v"(PC));     \
    asm volatile("global_load_dwordx4 %0, %1, off offset:448"  : "=&v"(R4) : "v"(PC));

#define WAITV(N)                                          \
    asm volatile("s_waitcnt vmcnt(" #N ")" ::: "memory"); \
    __builtin_amdgcn_sched_barrier(0);

    v4f A0, A1, A2, A3, A4, B0, B1, B2, B3, B4;

    if (blockIdx.y >= 1 && blockIdx.y <= 12) {
        // ---- interior strips: rows y-2..y+2 are exactly -448..+448 bytes ----
        const float* pc = p + o2;  // center-row per-lane address
        LOAD5(A0, A1, A2, A3, A4, pc); pc += 4 * HW;
        LOAD5(B0, B1, B2, B3, B4, pc); pc += 4 * HW;
        for (int k = 0; k + 4 <= NITER; k += 2) {
            WAITV(5);                                    // A ready, B in flight
            STEP(A0, A1, A2, A3, A4);
            LOAD5(A0, A1, A2, A3, A4, pc); pc += 4 * HW;
            WAITV(5);                                    // B ready, A' in flight
            STEP(B0, B1, B2, B3, B4);
            LOAD5(B0, B1, B2, B3, B4, pc); pc += 4 * HW;
        }
        WAITV(5);
        STEP(A0, A1, A2, A3, A4);
        WAITV(0);
        STEP(B0, B1, B2, B3, B4);
    } else {
        // ---- boundary strips (y-clamps active): proven C path ----
        A0 = *(const v4f*)(p + o0); A1 = *(const v4f*)(p + o1);
        A2 = *(const v4f*)(p + o2); A3 = *(const v4f*)(p + o3);
        A4 = *(const v4f*)(p + o4);
        p += 4 * HW;
        for (int k = 0; k + 2 <= NITER; k += 2) {
            B0 = *(const v4f*)(p + o0); B1 = *(const v4f*)(p + o1);
            B2 = *(const v4f*)(p + o2); B3 = *(const v4f*)(p + o3);
            B4 = *(const v4f*)(p + o4);
            STEP(A0, A1, A2, A3, A4);
            const float* pn = (k + 2 < NITER) ? p + 4 * HW : p;
            A0 = *(const v4f*)(pn + o0); A1 = *(const v4f*)(pn + o1);
            A2 = *(const v4f*)(pn + o2); A3 = *(const v4f*)(pn + o3);
            A4 = *(const v4f*)(pn + o4);
            STEP(B0, B1, B2, B3, B4);
            p = pn + 4 * HW;
        }
    }
#undef STEP
#undef LOAD5
#undef WAITV

    // ---- reduce across the 4 channel sub-groups (lanes q, q+16, q+32, q+48) ----
#define RED2(v) { v += __shfl_xor(v, 16, 64); v += __shfl_xor(v, 32, 64); }
    RED2(sA0) RED2(sA1) RED2(sA2) RED2(sA3)
    RED2(sB0) RED2(sB1) RED2(sB2) RED2(sB3)
    RED2(sC0) RED2(sC1) RED2(sC2) RED2(sC3)
    RED2(sD0) RED2(sD1) RED2(sD2) RED2(sD3)
    RED2(sE0) RED2(sE1) RED2(sE2) RED2(sE3)
    RED2(sF0) RED2(sF1) RED2(sF2) RED2(sF3)
#undef RED2

    if (lane < 14) {  // sc==0, q<14
        const int pix = b * HW + y * WW + 4 * q;
        if (WRITE_OUT) {
            v4f r;
            r.x = (float)(0.5 * ((double)sA0 / sqrt((double)sB0 * (double)sC0) +
                                 (double)sD0 / sqrt((double)sE0 * (double)sF0)));
            r.y = (float)(0.5 * ((double)sA1 / sqrt((double)sB1 * (double)sC1) +
                                 (double)sD1 / sqrt((double)sE1 * (double)sF1)));
            r.z = (float)(0.5 * ((double)sA2 / sqrt((double)sB2 * (double)sC2) +
                                 (double)sD2 / sqrt((double)sE2 * (double)sF2)));
            r.w = (float)(0.5 * ((double)sA3 / sqrt((double)sB3 * (double)sC3) +
                                 (double)sD3 / sqrt((double)sE3 * (double)sF3)));
            *(v4f*)(out + pix) = r;
        } else {
            float* slab = ws + (size_t)cg * 6 * NPIX;
            *(v4f*)(slab + 0 * NPIX + pix) = (v4f){sA0, sA1, sA2, sA3};
            *(v4f*)(slab + 1 * NPIX + pix) = (v4f){sB0, sB1, sB2, sB3};
            *(v4f*)(slab + 2 * NPIX + pix) = (v4f){sC0, sC1, sC2, sC3};
            *(v4f*)(slab + 3 * NPIX + pix) = (v4f){sD0, sD1, sD2, sD3};
            *(v4f*)(slab + 4 * NPIX + pix) = (v4f){sE0, sE1, sE2, sE3};
            *(v4f*)(slab + 5 * NPIX + pix) = (v4f){sF0, sF1, sF2, sF3};
        }
    }
}

__global__ void ComputeTotalSim_finalize(const float* __restrict__ ws,
                                         float* __restrict__ out) {
    const int i = blockIdx.x * blockDim.x + threadIdx.x;
    if (i < NPIX) {
        double a0 = 0, a1 = 0, a2 = 0, a3 = 0, a4 = 0, a5 = 0;
#pragma unroll
        for (int cg = 0; cg < CGROUPS; ++cg) {
            const float* slab = ws + (size_t)cg * 6 * NPIX;
            a0 += slab[0 * NPIX + i];
            a1 += slab[1 * NPIX + i];
            a2 += slab[2 * NPIX + i];
            a3 += slab[3 * NPIX + i];
            a4 += slab[4 * NPIX + i];
            a5 += slab[5 * NPIX + i];
        }
        out[i] = (float)(0.5 * (a0 / sqrt(a1 * a2) + a3 / sqrt(a4 * a5)));
    }
}

extern "C" void kernel_launch(void* const* d_in, const int* in_sizes, int n_in,
                              void* d_out, int out_size, void* d_ws, size_t ws_size,
                              hipStream_t stream) {
    const float* feat = (const float*)d_in[0];
    float* out = (float*)d_out;

    const size_t need = (size_t)CGROUPS * 6 * NPIX * sizeof(float);  // 9.6 MB
    if (ws_size >= need) {
        // Phase 1: per-cgroup slab partials (plain stores, every slot written
        // every call -> no memset needed). Phase 2: sum slabs + cosine.
        dim3 grid(CGROUPS, HH / 4, BB);  // 8 x 14 x 16 = 1792 blocks
        ComputeTotalSim_84267258347855_kernel<CC / (4 * CGROUPS), false>
            <<<grid, 256, 0, stream>>>(feat, (float*)d_ws, out);
        ComputeTotalSim_finalize<<<(NPIX + 255) / 256, 256, 0, stream>>>(
            (const float*)d_ws, out);
    } else {
        // Fallback: single cgroup covers all 512 channels, writes out directly.
        dim3 grid(1, HH / 4, BB);
        ComputeTotalSim_84267258347855_kernel<CC / 4, true>
            <<<grid, 256, 0, stream>>>(feat, nullptr, out);
    }
}